// Round 19
// baseline (220.711 us; speedup 1.0000x reference)
//
#include <hip/hip_runtime.h>
#include <hip/hip_bf16.h>
#include <cstdint>

// DistanceAwareSelfAttention: SLEN=1024, BSZ=8, H=16, D=64, EMB=1024, CLIP=10
// Pipeline: f2b3 convert -> GEMM1 (in_proj; q/k scatter to qkvt, V transposed
//           in-LDS to vt) -> flash attention (qk bias fused) -> GEMM2.
// R19: attn waves process 32 q-rows (two 16-row subtiles A/B, separate m/l
//      serializer chains — R15 lesson).  K/V fragment reads, staging, barriers
//      shared between subtiles: per-q-row LDS issues + staging traffic halve
//      (512 blocks).  GEMMs/f2b3 byte-identical to R18 (195.6 us).

typedef __attribute__((ext_vector_type(8))) __bf16 bf16x8;
typedef __attribute__((ext_vector_type(4))) __bf16 bf16x4;
typedef __attribute__((ext_vector_type(4))) short s16x4;
typedef __attribute__((ext_vector_type(4))) float f32x4;

#if __has_builtin(__builtin_amdgcn_exp2f)
#define EXP2F(x) __builtin_amdgcn_exp2f(x)
#else
#define EXP2F(x) exp2f(x)
#endif

#if __has_builtin(__builtin_amdgcn_mfma_f32_16x16x16bf16_1k)
#define PV_MFMA(ACC, AV, BV) \
  ACC = __builtin_amdgcn_mfma_f32_16x16x16bf16_1k( \
      __builtin_bit_cast(s16x4, AV), __builtin_bit_cast(s16x4, BV), ACC, 0, 0, 0)
#elif __has_builtin(__builtin_amdgcn_mfma_f32_16x16x16_bf16)
#define PV_MFMA(ACC, AV, BV) \
  ACC = __builtin_amdgcn_mfma_f32_16x16x16_bf16(AV, BV, ACC, 0, 0, 0)
#else
#define PV_MFMA(ACC, AV, BV)                                               \
  asm volatile("s_nop 1\n\tv_mfma_f32_16x16x16_bf16 %0, %1, %2, %0\n\t"    \
               "s_nop 7\n\ts_nop 7"                                        \
               : "+v"(ACC)                                                 \
               : "v"(__builtin_bit_cast(s16x4, AV)),                       \
                 "v"(__builtin_bit_cast(s16x4, BV)))
#endif

__device__ __forceinline__ void gload_lds16(const void* g, void* l) {
  __builtin_amdgcn_global_load_lds(
      (const __attribute__((address_space(1))) void*)g,
      (__attribute__((address_space(3))) void*)l, 16, 0, 0);
}

// one launch converting all three fp32 inputs to bf16
__global__ __launch_bounds__(256) void f2b3_kernel(
    const float* __restrict__ s0, __bf16* __restrict__ d0,
    const float* __restrict__ s1, __bf16* __restrict__ d1,
    const float* __restrict__ s2, __bf16* __restrict__ d2) {
  int i = (blockIdx.x * 256 + threadIdx.x) * 8;
  const float* s; __bf16* d; int off;
  if (i < 8388608) { s = s0; d = d0; off = i; }
  else if (i < 11534336) { s = s1; d = d1; off = i - 8388608; }
  else { s = s2; d = d2; off = i - 11534336; }
  float4 a = *(const float4*)(s + off);
  float4 b = *(const float4*)(s + off + 4);
  bf16x8 o;
  o[0] = (__bf16)a.x; o[1] = (__bf16)a.y; o[2] = (__bf16)a.z; o[3] = (__bf16)a.w;
  o[4] = (__bf16)b.x; o[5] = (__bf16)b.y; o[6] = (__bf16)b.z; o[7] = (__bf16)b.w;
  *(bf16x8*)(d + off) = o;
}

// ---- phase-interleaved GEMM (unchanged from R18) ----
#define STG8A(SL, TK, G)                                                      \
  gload_lds16(A + (size_t)(m0 + (G) * 64 + (tid >> 3)) * K + (TK) * 64 + sgc, \
              (void*)&sG[SL][(G) * 4096 + wave * 512]);
#define STG8B(SL, TK, G)                                                      \
  gload_lds16(Bp + (size_t)(n0 + (G) * 64 + (tid >> 3)) * K + (TK) * 64 + sgc,\
              (void*)&sG[SL][16384 + (G) * 4096 + wave * 512]);

#define GPH(SL, MP, NP, STAGE_STMT, TAIL_STMT)                                  \
  {                                                                             \
    bf16x8 af[2][2], bfr[2][2];                                                 \
    _Pragma("unroll") for (int mi = 0; mi < 2; ++mi)                            \
      _Pragma("unroll") for (int kk = 0; kk < 2; ++kk)                          \
        af[mi][kk] = *(const bf16x8*)&sG[SL][                                   \
            (wr * 64 + ((MP) * 2 + mi) * 16 + lr) * 64 +                        \
            (((kk * 4 + lg) ^ (lr & 7)) * 8)];                                  \
    _Pragma("unroll") for (int ni = 0; ni < 2; ++ni)                            \
      _Pragma("unroll") for (int kk = 0; kk < 2; ++kk)                          \
        bfr[ni][kk] = *(const bf16x8*)&sG[SL][16384 +                           \
            (wc * 64 + ((NP) * 2 + ni) * 16 + lr) * 64 +                        \
            (((kk * 4 + lg) ^ (lr & 7)) * 8)];                                  \
    STAGE_STMT                                                                  \
    __builtin_amdgcn_s_barrier();                                               \
    asm volatile("s_waitcnt lgkmcnt(0)" ::: "memory");                          \
    __builtin_amdgcn_sched_barrier(0);                                          \
    __builtin_amdgcn_s_setprio(1);                                              \
    _Pragma("unroll") for (int mi = 0; mi < 2; ++mi)                            \
      _Pragma("unroll") for (int ni = 0; ni < 2; ++ni)                          \
        _Pragma("unroll") for (int kk = 0; kk < 2; ++kk)                        \
          acc[(MP) * 2 + mi][(NP) * 2 + ni] =                                   \
              __builtin_amdgcn_mfma_f32_16x16x32_bf16(                          \
                  af[mi][kk], bfr[ni][kk],                                      \
                  acc[(MP) * 2 + mi][(NP) * 2 + ni], 0, 0, 0);                  \
    __builtin_amdgcn_s_setprio(0);                                              \
    TAIL_STMT                                                                   \
    __builtin_amdgcn_s_barrier();                                               \
  }

#define GTILE(SL, SS, TK2, DOSTG, WAITC)                                        \
  GPH(SL, 0, 0, if (DOSTG) { STG8A(SS, TK2, 0) STG8A(SS, TK2, 1) }, )           \
  GPH(SL, 0, 1, if (DOSTG) { STG8A(SS, TK2, 2) STG8A(SS, TK2, 3) }, )           \
  GPH(SL, 1, 0, if (DOSTG) { STG8B(SS, TK2, 0) }, )                             \
  GPH(SL, 1, 1, if (DOSTG) { STG8B(SS, TK2, 1) },                               \
      if ((WAITC) == 6) { asm volatile("s_waitcnt vmcnt(6)" ::: "memory"); }    \
      else if ((WAITC) == 0) { asm volatile("s_waitcnt vmcnt(0)" ::: "memory"); })

template <int EPI>
__global__ __launch_bounds__(512) void gemm8p(
    const __bf16* __restrict__ A, const __bf16* __restrict__ Bp,
    const float* __restrict__ bias, int K,
    float* __restrict__ outF, __bf16* __restrict__ outT,
    __bf16* __restrict__ outV, int N, int NT, int CPX) {
  __shared__ __align__(16) __bf16 sG[3][24576];  // per slot: A 256x64, B 128x64
  const int tid = threadIdx.x;
  const int wave = tid >> 6, lane = tid & 63;
  const int lg = lane >> 4, lr = lane & 15;
  const int wr = wave >> 1, wc = wave & 1;   // 4M x 2N wave grid
  const int lid = (blockIdx.x & 7) * CPX + (blockIdx.x >> 3);
  const int m0 = (lid / NT) * 256;
  const int n0 = (lid % NT) * 128;

  const int sgc = ((tid & 7) ^ ((tid >> 3) & 7)) * 8;

  f32x4 acc[4][4] = {};

  STG8A(0, 0, 0) STG8A(0, 0, 1) STG8A(0, 0, 2) STG8A(0, 0, 3)
  STG8B(0, 0, 0) STG8B(0, 0, 1)
  STG8A(1, 1, 0) STG8A(1, 1, 1) STG8A(1, 1, 2) STG8A(1, 1, 3)
  STG8B(1, 1, 0) STG8B(1, 1, 1)
  asm volatile("s_waitcnt vmcnt(6)" ::: "memory");
  __builtin_amdgcn_s_barrier();

  GTILE(0, 2, 2, 1, 6)
  GTILE(1, 0, 3, 1, 6)
  GTILE(2, 1, 4, 1, 6)
  GTILE(0, 2, 5, 1, 6)
  GTILE(1, 0, 6, 1, 6)
  GTILE(2, 1, 7, 1, 6)
  GTILE(0, 2, 8, 1, 6)
  GTILE(1, 0, 9, 1, 6)
  GTILE(2, 1, 10, 1, 6)
  GTILE(0, 2, 11, 1, 6)
  GTILE(1, 0, 12, 1, 6)
  GTILE(2, 1, 13, 1, 6)
  GTILE(0, 2, 14, 1, 6)
  GTILE(1, 0, 15, 1, 6)
  GTILE(2, 1, 16, 0, 0)
  GTILE(0, 2, 17, 0, 2)

  if constexpr (EPI == 0) {
    const int tt = n0 >> 10;
    if (tt == 2) {
      // fused vtrans: acc -> LDS [h2][b][d][s32] -> vt (coalesced 64B rows)
      __bf16* vtl = &sG[0][0];
#pragma unroll
      for (int mf = 0; mf < 4; ++mf) {
#pragma unroll
        for (int nf = 0; nf < 4; ++nf) {
          const int gn = n0 + wc * 64 + nf * 16 + lr;
          const float bv = bias[gn];
          const int d = nf * 16 + lr;
#pragma unroll
          for (int rg = 0; rg < 4; ++rg) {
            const int row = wr * 64 + mf * 16 + lg * 4 + rg;
            const float v = acc[mf][nf][rg] + bv;
            vtl[((size_t)((wc * 8 + (row & 7)) * 64 + d) << 5) + (row >> 3)] =
                (__bf16)v;
          }
        }
      }
      __syncthreads();
      const int s0g = m0 >> 3;
      const int hh = (n0 >> 6) & 15;
#pragma unroll
      for (int rr = 0; rr < 2; ++rr) {
        const int r = tid + rr * 512;
        const int hl = r >> 9, bb = (r >> 6) & 7, dd = r & 63;
        __bf16* dst = outV + ((size_t)((bb * 16 + hh + hl) * 64 + dd) << 10) + s0g;
        const __bf16* src = &vtl[(size_t)r << 5];
#pragma unroll
        for (int j = 0; j < 4; ++j)
          *(bf16x8*)&dst[j * 8] = *(const bf16x8*)&src[j * 8];
      }
      return;
    }
  }

#pragma unroll
  for (int mf = 0; mf < 4; ++mf) {
    const int gm0 = m0 + wr * 64 + mf * 16 + lg * 4;
#pragma unroll
    for (int nf = 0; nf < 4; ++nf) {
      const int gn = n0 + wc * 64 + nf * 16 + lr;
      const float bv = bias[gn];
#pragma unroll
      for (int rg = 0; rg < 4; ++rg) {
        const int gm = gm0 + rg;
        float v = acc[mf][nf][rg] + bv;
        if constexpr (EPI == 0) {
          int t = gn >> 10, h = (gn >> 6) & 15, d = gn & 63;
          int s = gm >> 3, b = gm & 7;
          if (t == 0) v *= 0.18033688011112042f;  // d^-0.5 * log2(e)
          outT[(((size_t)((t * 8 + b) * 16 + h) * 1024 + s) << 6) + d] = (__bf16)v;
        } else {
          outF[(size_t)gm * N + gn] = v;
        }
      }
    }
  }
}

// ---- attn per-tile macro: two 16-row q-subtiles (A at sb+lr, B at sb+16+lr)
// share all K/V fragment reads, staging and barriers.  KT/KC/KS/VC/VS LITERAL.
#define ATTN_TILE(KT, KC, KS, VC, VS)                                           \
  {                                                                             \
    if ((KT) < 15)                                                              \
      gload_lds16(vtp + (size_t)srow * 1024 + ((KT) + 1) * 64 + sc8,            \
                  &sV[VS][wave * 512]);                                         \
    if ((KT) < 14)                                                              \
      gload_lds16(kp + (size_t)((KT) * 64 + 128 + srow) * 64 + sc8,             \
                  &sK[KS][wave * 512]);                                         \
    f32x4 sfA[4], sfB[4];                                                       \
    __builtin_amdgcn_s_setprio(1);                                              \
    _Pragma("unroll") for (int tj = 0; tj < 4; ++tj) {                          \
      const int t = tj * 16 + lr;                                               \
      bf16x8 bk0 = *(const bf16x8*)&sK[KC][t * 64 + ((lg ^ (t & 7)) * 8)];      \
      bf16x8 bk1 = *(const bf16x8*)&sK[KC][t * 64 + (((4 + lg) ^ (t & 7)) * 8)];\
      f32x4 zA = {}, zB = {};                                                   \
      zA = __builtin_amdgcn_mfma_f32_16x16x32_bf16(bk0, aqA[0], zA, 0, 0, 0);   \
      zA = __builtin_amdgcn_mfma_f32_16x16x32_bf16(bk1, aqA[1], zA, 0, 0, 0);   \
      zB = __builtin_amdgcn_mfma_f32_16x16x32_bf16(bk0, aqB[0], zB, 0, 0, 0);   \
      zB = __builtin_amdgcn_mfma_f32_16x16x32_bf16(bk1, aqB[1], zB, 0, 0, 0);   \
      sfA[tj] = zA; sfB[tj] = zB;                                               \
    }                                                                           \
    __builtin_amdgcn_s_setprio(0);                                              \
    const bool inband = ((KT) * 64 <= sb + 40) && ((KT) * 64 + 63 >= sb - 9);   \
    if (inband) {                                                               \
      _Pragma("unroll") for (int tj = 0; tj < 4; ++tj) {                        \
        _Pragma("unroll") for (int rg = 0; rg < 4; ++rg) {                      \
          const int t = (KT) * 64 + tj * 16 + lg * 4 + rg;                      \
          {                                                                     \
            const int dd = t - sA;                                              \
            const int ad = dd < 0 ? -dd : dd;                                   \
            if (ad <= 9) {                                                      \
              const float val = sfA[tj][rg] + sBD[wave][lr][ad];                \
              sfA[tj][rg] = val;                                                \
              band[wave][lr][dd + 9] = (__bf16)val;                             \
            }                                                                   \
          }                                                                     \
          {                                                                     \
            const int dd = t - sB2;                                             \
            const int ad = dd < 0 ? -dd : dd;                                   \
            if (ad <= 9) {                                                      \
              const float val = sfB[tj][rg] + sBD[wave][16 + lr][ad];           \
              sfB[tj][rg] = val;                                                \
              band[wave][16 + lr][dd + 9] = (__bf16)val;                        \
            }                                                                   \
          }                                                                     \
        }                                                                       \
      }                                                                         \
    }                                                                           \
    {                                                                           \
      float vmA[4], vmB[4];                                                     \
      _Pragma("unroll") for (int tj = 0; tj < 4; ++tj) {                        \
        vmA[tj] = fmaxf(fmaxf(sfA[tj][0], sfA[tj][1]),                          \
                        fmaxf(sfA[tj][2], sfA[tj][3]));                         \
        vmB[tj] = fmaxf(fmaxf(sfB[tj][0], sfB[tj][1]),                          \
                        fmaxf(sfB[tj][2], sfB[tj][3]));                         \
      }                                                                         \
      float vmaxA = fmaxf(fmaxf(vmA[0], vmA[1]), fmaxf(vmA[2], vmA[3]));        \
      float vmaxB = fmaxf(fmaxf(vmB[0], vmB[1]), fmaxf(vmB[2], vmB[3]));        \
      vmaxA = fmaxf(vmaxA, __shfl_xor(vmaxA, 16, 64));                          \
      vmaxA = fmaxf(vmaxA, __shfl_xor(vmaxA, 32, 64));                          \
      vmaxB = fmaxf(vmaxB, __shfl_xor(vmaxB, 16, 64));                          \
      vmaxB = fmaxf(vmaxB, __shfl_xor(vmaxB, 32, 64));                          \
      if (__any(vmaxA > mA + 8.f)) {                                            \
        const float mn = fmaxf(mA, vmaxA);                                      \
        const float scl = EXP2F(mA - mn);                                       \
        mA = mn; lA *= scl;                                                     \
        _Pragma("unroll") for (int dj = 0; dj < 4; ++dj)                        \
          _Pragma("unroll") for (int rg = 0; rg < 4; ++rg)                      \
            o_accA[dj][rg] *= scl;                                              \
      }                                                                         \
      if (__any(vmaxB > mB + 8.f)) {                                            \
        const float mn = fmaxf(mB, vmaxB);                                      \
        const float scl = EXP2F(mB - mn);                                       \
        mB = mn; lB *= scl;                                                     \
        _Pragma("unroll") for (int dj = 0; dj < 4; ++dj)                        \
          _Pragma("unroll") for (int rg = 0; rg < 4; ++rg)                      \
            o_accB[dj][rg] *= scl;                                              \
      }                                                                         \
    }                                                                           \
    bf16x4 pbvA[4], pbvB[4];                                                    \
    {                                                                           \
      float rsA = 0.f, rsB = 0.f;                                               \
      _Pragma("unroll") for (int tj = 0; tj < 4; ++tj) {                        \
        float a0 = EXP2F(sfA[tj][0] - mA), a1 = EXP2F(sfA[tj][1] - mA);         \
        float a2 = EXP2F(sfA[tj][2] - mA), a3 = EXP2F(sfA[tj][3] - mA);         \
        rsA += (a0 + a1) + (a2 + a3);                                           \
        pbvA[tj][0] = (__bf16)a0; pbvA[tj][1] = (__bf16)a1;                     \
        pbvA[tj][2] = (__bf16)a2; pbvA[tj][3] = (__bf16)a3;                     \
        float b0 = EXP2F(sfB[tj][0] - mB), b1 = EXP2F(sfB[tj][1] - mB);         \
        float b2 = EXP2F(sfB[tj][2] - mB), b3 = EXP2F(sfB[tj][3] - mB);         \
        rsB += (b0 + b1) + (b2 + b3);                                           \
        pbvB[tj][0] = (__bf16)b0; pbvB[tj][1] = (__bf16)b1;                     \
        pbvB[tj][2] = (__bf16)b2; pbvB[tj][3] = (__bf16)b3;                     \
      }                                                                         \
      rsA += __shfl_xor(rsA, 16, 64);                                           \
      rsA += __shfl_xor(rsA, 32, 64);                                           \
      rsB += __shfl_xor(rsB, 16, 64);                                           \
      rsB += __shfl_xor(rsB, 32, 64);                                           \
      lA += rsA; lB += rsB;                                                     \
    }                                                                           \
    __builtin_amdgcn_s_setprio(1);                                              \
    _Pragma("unroll") for (int tj = 0; tj < 4; ++tj) {                          \
      _Pragma("unroll") for (int dj = 0; dj < 4; ++dj) {                        \
        const int d = dj * 16 + lr;                                             \
        const int ch = (2 * tj + (lg >> 1)) ^ (d & 7);                          \
        const bf16x4 av = *(const bf16x4*)&sV[VC][d * 64 + ch * 8 + (lg & 1) * 4]; \
        PV_MFMA(o_accA[dj], av, pbvA[tj]);                                      \
        PV_MFMA(o_accB[dj], av, pbvB[tj]);                                      \
      }                                                                         \
    }                                                                           \
    __builtin_amdgcn_s_setprio(0);                                              \
    if ((KT) < 14) {                                                            \
      asm volatile("s_waitcnt vmcnt(1)" ::: "memory");                          \
    } else if ((KT) == 14) {                                                    \
      asm volatile("s_waitcnt vmcnt(0)" ::: "memory");                          \
    }                                                                           \
    if ((KT) < 15) __builtin_amdgcn_s_barrier();                                \
  }

// Flash attention w/ distance band, qk-bias FUSED, 32 q-rows/wave (2 subtiles).
// 8 waves -> 256 q-rows/block, 512 blocks.  Swapped QK^T, per-lane softmax,
// zero-shuffle PV; K triple-buffered (2-ahead), V double-buffered (1-ahead).
__global__ __launch_bounds__(512) void attn_kernel(
    const __bf16* __restrict__ qkv, const __bf16* __restrict__ vt,
    const float* __restrict__ kde, const float* __restrict__ vde,
    __bf16* __restrict__ O) {
  __shared__ __align__(16) __bf16 sK[3][4096];   // [64 t][64 k], 16B-chunk XOR swizzled
  __shared__ __align__(16) __bf16 sV[2][4096];   // [64 d][64 t], 16B-chunk XOR swizzled
  __shared__ __bf16 band[8][32][20];             // band logits (log2 dom), slot=(t-s)+9
  __shared__ float sBD[8][32][10];               // fused qk distance bias per q-row
  const int tid = threadIdx.x, wave = tid >> 6, lane = tid & 63;
  const int lg = lane >> 4, lr = lane & 15;
  // XCD-chunked bijective swizzle: 512 blocks -> 8 chunks of 64.
  const int lid = (blockIdx.x & 7) * 64 + (blockIdx.x >> 3);
  const int bh = lid >> 2;
  const int stile = lid & 3;
  const int sb = stile * 256 + wave * 32;
  const int b = bh >> 4, h = bh & 15;
  const __bf16* qp = qkv + (size_t)bh * 65536;
  const __bf16* kp = qkv + (size_t)(128 + bh) * 65536;
  const __bf16* vtp = vt + (size_t)bh * 65536;

  const int srow = tid >> 3;
  const int sc8 = ((tid & 7) ^ (srow & 7)) * 8;

  // prologue staging: K0, V0, K1 (vmcnt(1) leaves K1 in flight)
  gload_lds16(kp + (size_t)srow * 64 + sc8, &sK[0][wave * 512]);
  gload_lds16(vtp + (size_t)srow * 1024 + sc8, &sV[0][wave * 512]);
  gload_lds16(kp + (size_t)(64 + srow) * 64 + sc8, &sK[1][wave * 512]);

  {
    __bf16* bf = &band[0][0][0];
    for (int i = tid; i < 8 * 32 * 20; i += 512) bf[i] = (__bf16)(-1e30f);
  }

  bf16x8 aqA[2], aqB[2];
#pragma unroll
  for (int kk = 0; kk < 2; ++kk) {
    aqA[kk] = *(const bf16x8*)&qp[(size_t)(sb + lr) * 64 + kk * 32 + lg * 8];
    aqB[kk] = *(const bf16x8*)&qp[(size_t)(sb + 16 + lr) * 64 + kk * 32 + lg * 8];
  }

  // ---- fused qk distance-bias for both subtile rows ----
  {
    float kd10[16];
#pragma unroll
    for (int e = 0; e < 16; ++e)
      kd10[e] = kde[640 + (e >> 3) * 32 + lg * 8 + (e & 7)];
#pragma unroll
    for (int c = 0; c < 10; ++c) {
      float accA = 0.f, accB = 0.f;
#pragma unroll
      for (int e = 0; e < 16; ++e) {
        const float kd = kde[c * 64 + (e >> 3) * 32 + lg * 8 + (e & 7)] - kd10[e];
        accA += (float)aqA[e >> 3][e & 7] * kd;
        accB += (float)aqB[e >> 3][e & 7] * kd;
      }
      accA += __shfl_xor(accA, 16, 64);
      accA += __shfl_xor(accA, 32, 64);
      accB += __shfl_xor(accB, 16, 64);
      accB += __shfl_xor(accB, 32, 64);
      if (lg == 0) {
        sBD[wave][lr][c] = accA;
        sBD[wave][16 + lr][c] = accB;
      }
    }
  }

  f32x4 o_accA[4] = {}, o_accB[4] = {};
  float mA = -1e30f, lA = 0.f, mB = -1e30f, lB = 0.f;
  const int sA = sb + lr;
  const int sB2 = sb + 16 + lr;

  asm volatile("s_waitcnt vmcnt(1)" ::: "memory");
  __builtin_amdgcn_s_barrier();

  //            KT  KC KS VC VS
  ATTN_TILE( 0, 0, 2, 0, 1)
  ATTN_TILE( 1, 1, 0, 1, 0)
  ATTN_TILE( 2, 2, 1, 0, 1)
  ATTN_TILE( 3, 0, 2, 1, 0)
  ATTN_TILE( 4, 1, 0, 0, 1)
  ATTN_TILE( 5, 2, 1, 1, 0)
  ATTN_TILE( 6, 0, 2, 0, 1)
  ATTN_TILE( 7, 1, 0, 1, 0)
  ATTN_TILE( 8, 2, 1, 0, 1)
  ATTN_TILE( 9, 0, 2, 1, 0)
  ATTN_TILE(10, 1, 0, 0, 1)
  ATTN_TILE(11, 2, 1, 1, 0)
  ATTN_TILE(12, 0, 2, 0, 1)
  ATTN_TILE(13, 1, 0, 1, 0)
  ATTN_TILE(14, 2, 1, 0, 1)
  ATTN_TILE(15, 0, 2, 1, 0)

  // ---- epilogue: normalize + v_dist band correction for both subtiles ----
#pragma unroll
  for (int sub = 0; sub < 2; ++sub) {
    const int sr = sub ? sB2 : sA;
    const int br = sub ? 16 + lr : lr;
    const float mm = sub ? mB : mA;
    const float inv = 1.f / (sub ? lB : lA);
    const f32x4* oa = sub ? o_accB : o_accA;
    float psum[10];
    psum[0] = EXP2F((float)band[wave][br][9] - mm);
#pragma unroll
    for (int c = 1; c < 10; ++c)
      psum[c] = EXP2F((float)band[wave][br][9 - c] - mm) +
                EXP2F((float)band[wave][br][9 + c] - mm);
#pragma unroll
    for (int dj = 0; dj < 4; ++dj) {
      bf16x4 ov;
#pragma unroll
      for (int rg = 0; rg < 4; ++rg) {
        const int d = dj * 16 + lg * 4 + rg;
        float acc2 = 0.f;
#pragma unroll
        for (int c = 0; c < 10; ++c)
          acc2 += psum[c] * (vde[c * 64 + d] - vde[640 + d]);
        ov[rg] = (__bf16)((oa[dj][rg] + acc2) * inv + vde[640 + d]);
      }
      *(bf16x4*)&O[((size_t)(sr * 8 + b)) * 1024 + h * 64 + dj * 16 + lg * 4] = ov;
    }
  }
}

extern "C" void kernel_launch(void* const* d_in, const int* in_sizes, int n_in,
                              void* d_out, int out_size, void* d_ws, size_t ws_size,
                              hipStream_t stream) {
  (void)in_sizes; (void)n_in; (void)out_size; (void)ws_size;
  const float* inputs = (const float*)d_in[0];
  const float* W_in   = (const float*)d_in[1];
  const float* b_in   = (const float*)d_in[2];
  const float* kde    = (const float*)d_in[3];
  const float* vde    = (const float*)d_in[4];
  const float* W_out  = (const float*)d_in[5];
  const float* b_out  = (const float*)d_in[6];
  float* out = (float*)d_out;

  char* ws = (char*)d_ws;
  __bf16* qkvt  = (__bf16*)(ws);              // (3,8,16,1024,64) bf16 (V third unused)
  __bf16* vt    = (__bf16*)(ws + 50331648);   // (128,64,1024)  bf16
  __bf16* Xb    = (__bf16*)(ws + 75497472);   // (8192,1024)    bf16
  __bf16* Ob    = (__bf16*)(ws + 75497472);   // reuse Xb region after GEMM1
  __bf16* Wb_in = (__bf16*)(ws + 92274688);   // (3072,1024)    bf16
  __bf16* Wb_out= (__bf16*)(ws + 98566144);   // (1024,1024)    bf16

  f2b3_kernel<<<6144, 256, 0, stream>>>(inputs, Xb, W_in, Wb_in, W_out, Wb_out);

  // GEMM1: 32 M-bands x 24 N-tiles = 768 blocks (3 FULL rounds, CPX=96)
  gemm8p<0><<<768, 512, 0, stream>>>(Xb, Wb_in, b_in, 1024, nullptr, qkvt, vt, 3072, 24, 96);
  attn_kernel<<<512, 512, 0, stream>>>(qkvt, vt, kde, vde, Ob);
  // GEMM2: 32 x 8 = 256 blocks (1 FULL round, CPX=32)
  gemm8p<1><<<256, 512, 0, stream>>>(Ob, Wb_out, b_out, 1024, out, nullptr, nullptr, 1024, 8, 32);
}

// Round 20
// 195.131 us; speedup vs baseline: 1.1311x; 1.1311x over previous
//
#include <hip/hip_runtime.h>
#include <hip/hip_bf16.h>
#include <cstdint>

// DistanceAwareSelfAttention: SLEN=1024, BSZ=8, H=16, D=64, EMB=1024, CLIP=10
// Pipeline: f2b3 convert -> GEMM1 (in_proj; q/k scatter to qkvt, V TRANSPOSED
//           IN-LDS and written to vt) -> flash attention (qk bias fused) -> GEMM2.
// R20: revert to R18 (195.6 us best).  R19's 32-q-rows/wave halved occupancy
//      (39.7->22.3%, VGPR 80, LDS 61KB) — the q-rows-per-wave axis is closed
//      from both ends (R11 32x32 MFMA, R19 dual subtiles both lose).
//      R18 = phase-interleaved triple-buffered GEMMs (counted vmcnt(6)),
//      fused in-LDS vtrans, fused qk-bias attn with counted-vmcnt K/V staging.

typedef __attribute__((ext_vector_type(8))) __bf16 bf16x8;
typedef __attribute__((ext_vector_type(4))) __bf16 bf16x4;
typedef __attribute__((ext_vector_type(4))) short s16x4;
typedef __attribute__((ext_vector_type(4))) float f32x4;

#if __has_builtin(__builtin_amdgcn_exp2f)
#define EXP2F(x) __builtin_amdgcn_exp2f(x)
#else
#define EXP2F(x) exp2f(x)
#endif

#if __has_builtin(__builtin_amdgcn_mfma_f32_16x16x16bf16_1k)
#define PV_MFMA(ACC, AV, BV) \
  ACC = __builtin_amdgcn_mfma_f32_16x16x16bf16_1k( \
      __builtin_bit_cast(s16x4, AV), __builtin_bit_cast(s16x4, BV), ACC, 0, 0, 0)
#elif __has_builtin(__builtin_amdgcn_mfma_f32_16x16x16_bf16)
#define PV_MFMA(ACC, AV, BV) \
  ACC = __builtin_amdgcn_mfma_f32_16x16x16_bf16(AV, BV, ACC, 0, 0, 0)
#else
#define PV_MFMA(ACC, AV, BV)                                               \
  asm volatile("s_nop 1\n\tv_mfma_f32_16x16x16_bf16 %0, %1, %2, %0\n\t"    \
               "s_nop 7\n\ts_nop 7"                                        \
               : "+v"(ACC)                                                 \
               : "v"(__builtin_bit_cast(s16x4, AV)),                       \
                 "v"(__builtin_bit_cast(s16x4, BV)))
#endif

__device__ __forceinline__ void gload_lds16(const void* g, void* l) {
  __builtin_amdgcn_global_load_lds(
      (const __attribute__((address_space(1))) void*)g,
      (__attribute__((address_space(3))) void*)l, 16, 0, 0);
}

// one launch converting all three fp32 inputs to bf16
__global__ __launch_bounds__(256) void f2b3_kernel(
    const float* __restrict__ s0, __bf16* __restrict__ d0,
    const float* __restrict__ s1, __bf16* __restrict__ d1,
    const float* __restrict__ s2, __bf16* __restrict__ d2) {
  int i = (blockIdx.x * 256 + threadIdx.x) * 8;
  const float* s; __bf16* d; int off;
  if (i < 8388608) { s = s0; d = d0; off = i; }
  else if (i < 11534336) { s = s1; d = d1; off = i - 8388608; }
  else { s = s2; d = d2; off = i - 11534336; }
  float4 a = *(const float4*)(s + off);
  float4 b = *(const float4*)(s + off + 4);
  bf16x8 o;
  o[0] = (__bf16)a.x; o[1] = (__bf16)a.y; o[2] = (__bf16)a.z; o[3] = (__bf16)a.w;
  o[4] = (__bf16)b.x; o[5] = (__bf16)b.y; o[6] = (__bf16)b.z; o[7] = (__bf16)b.w;
  *(bf16x8*)(d + off) = o;
}

// ---- phase-interleaved GEMM: C[m][n] = sum_k A[m][k]*B[n][k] + bias[n].
// 256x128 tile, BK=64, 8 waves (4Mx2N, 64x64 C per wave), triple-buffered
// K-tile slots.  Slot layout: sG[slot] = A[256*64] then B[128*64] elements.
// 16B-chunk XOR swizzle (chunk ^= row&7) on stage SOURCE and fragment reads.
// EPI 0: q/k scatter to qkvt (q scaled 0.125*log2e); V blocks -> in-LDS
//        transpose -> vt (b*16+h, d, s).  EPI 1: fp32 out.

#define STG8A(SL, TK, G)                                                      \
  gload_lds16(A + (size_t)(m0 + (G) * 64 + (tid >> 3)) * K + (TK) * 64 + sgc, \
              (void*)&sG[SL][(G) * 4096 + wave * 512]);
#define STG8B(SL, TK, G)                                                      \
  gload_lds16(Bp + (size_t)(n0 + (G) * 64 + (tid >> 3)) * K + (TK) * 64 + sgc,\
              (void*)&sG[SL][16384 + (G) * 4096 + wave * 512]);

// one phase: quadrant (MP,NP) of slot SL.  8 ds_read_b128 + stage + 8 MFMA.
#define GPH(SL, MP, NP, STAGE_STMT, TAIL_STMT)                                  \
  {                                                                             \
    bf16x8 af[2][2], bfr[2][2];                                                 \
    _Pragma("unroll") for (int mi = 0; mi < 2; ++mi)                            \
      _Pragma("unroll") for (int kk = 0; kk < 2; ++kk)                          \
        af[mi][kk] = *(const bf16x8*)&sG[SL][                                   \
            (wr * 64 + ((MP) * 2 + mi) * 16 + lr) * 64 +                        \
            (((kk * 4 + lg) ^ (lr & 7)) * 8)];                                  \
    _Pragma("unroll") for (int ni = 0; ni < 2; ++ni)                            \
      _Pragma("unroll") for (int kk = 0; kk < 2; ++kk)                          \
        bfr[ni][kk] = *(const bf16x8*)&sG[SL][16384 +                           \
            (wc * 64 + ((NP) * 2 + ni) * 16 + lr) * 64 +                        \
            (((kk * 4 + lg) ^ (lr & 7)) * 8)];                                  \
    STAGE_STMT                                                                  \
    __builtin_amdgcn_s_barrier();                                               \
    asm volatile("s_waitcnt lgkmcnt(0)" ::: "memory");                          \
    __builtin_amdgcn_sched_barrier(0);                                          \
    __builtin_amdgcn_s_setprio(1);                                              \
    _Pragma("unroll") for (int mi = 0; mi < 2; ++mi)                            \
      _Pragma("unroll") for (int ni = 0; ni < 2; ++ni)                          \
        _Pragma("unroll") for (int kk = 0; kk < 2; ++kk)                        \
          acc[(MP) * 2 + mi][(NP) * 2 + ni] =                                   \
              __builtin_amdgcn_mfma_f32_16x16x32_bf16(                          \
                  af[mi][kk], bfr[ni][kk],                                      \
                  acc[(MP) * 2 + mi][(NP) * 2 + ni], 0, 0, 0);                  \
    __builtin_amdgcn_s_setprio(0);                                              \
    TAIL_STMT                                                                   \
    __builtin_amdgcn_s_barrier();                                               \
  }

// one K-tile: 4 quadrant phases; stages tile TK2 -> slot SS (=(T+2)%3, never
// the slot being read); WAITC: 6 = vmcnt(6) boundary, 0 = vmcnt(0), 2 = none.
#define GTILE(SL, SS, TK2, DOSTG, WAITC)                                        \
  GPH(SL, 0, 0, if (DOSTG) { STG8A(SS, TK2, 0) STG8A(SS, TK2, 1) }, )           \
  GPH(SL, 0, 1, if (DOSTG) { STG8A(SS, TK2, 2) STG8A(SS, TK2, 3) }, )           \
  GPH(SL, 1, 0, if (DOSTG) { STG8B(SS, TK2, 0) }, )                             \
  GPH(SL, 1, 1, if (DOSTG) { STG8B(SS, TK2, 1) },                               \
      if ((WAITC) == 6) { asm volatile("s_waitcnt vmcnt(6)" ::: "memory"); }    \
      else if ((WAITC) == 0) { asm volatile("s_waitcnt vmcnt(0)" ::: "memory"); })

template <int EPI>
__global__ __launch_bounds__(512) void gemm8p(
    const __bf16* __restrict__ A, const __bf16* __restrict__ Bp,
    const float* __restrict__ bias, int K,
    float* __restrict__ outF, __bf16* __restrict__ outT,
    __bf16* __restrict__ outV, int N, int NT, int CPX) {
  __shared__ __align__(16) __bf16 sG[3][24576];  // per slot: A 256x64, B 128x64
  const int tid = threadIdx.x;
  const int wave = tid >> 6, lane = tid & 63;
  const int lg = lane >> 4, lr = lane & 15;
  const int wr = wave >> 1, wc = wave & 1;   // 4M x 2N wave grid
  const int lid = (blockIdx.x & 7) * CPX + (blockIdx.x >> 3);
  const int m0 = (lid / NT) * 256;
  const int n0 = (lid % NT) * 128;

  // staging: 512 threads cover 64 rows x 128B; source chunk XOR'd by row&7
  const int sgc = ((tid & 7) ^ ((tid >> 3) & 7)) * 8;

  f32x4 acc[4][4] = {};

  // prologue: stage K-tiles 0 (slot 0) and 1 (slot 1); 12 loads
  STG8A(0, 0, 0) STG8A(0, 0, 1) STG8A(0, 0, 2) STG8A(0, 0, 3)
  STG8B(0, 0, 0) STG8B(0, 0, 1)
  STG8A(1, 1, 0) STG8A(1, 1, 1) STG8A(1, 1, 2) STG8A(1, 1, 3)
  STG8B(1, 1, 0) STG8B(1, 1, 1)
  asm volatile("s_waitcnt vmcnt(6)" ::: "memory");  // tile0 done; tile1 in flight
  __builtin_amdgcn_s_barrier();

  GTILE(0, 2, 2, 1, 6)
  GTILE(1, 0, 3, 1, 6)
  GTILE(2, 1, 4, 1, 6)
  GTILE(0, 2, 5, 1, 6)
  GTILE(1, 0, 6, 1, 6)
  GTILE(2, 1, 7, 1, 6)
  GTILE(0, 2, 8, 1, 6)
  GTILE(1, 0, 9, 1, 6)
  GTILE(2, 1, 10, 1, 6)
  GTILE(0, 2, 11, 1, 6)
  GTILE(1, 0, 12, 1, 6)
  GTILE(2, 1, 13, 1, 6)
  GTILE(0, 2, 14, 1, 6)
  GTILE(1, 0, 15, 1, 6)
  GTILE(2, 1, 16, 0, 0)
  GTILE(0, 2, 17, 0, 2)

  if constexpr (EPI == 0) {
    const int tt = n0 >> 10;  // block-uniform: 0/1 = q/k, 2 = V
    if (tt == 2) {
      // ---- fused vtrans: acc -> LDS [h2][b][d][s32] -> vt (coalesced 64B rows)
      __bf16* vtl = &sG[0][0];  // 64KB; all main-loop reads done after final barrier
#pragma unroll
      for (int mf = 0; mf < 4; ++mf) {
#pragma unroll
        for (int nf = 0; nf < 4; ++nf) {
          const int gn = n0 + wc * 64 + nf * 16 + lr;
          const float bv = bias[gn];
          const int d = nf * 16 + lr;
#pragma unroll
          for (int rg = 0; rg < 4; ++rg) {
            const int row = wr * 64 + mf * 16 + lg * 4 + rg;  // 0..255
            const float v = acc[mf][nf][rg] + bv;
            vtl[((size_t)((wc * 8 + (row & 7)) * 64 + d) << 5) + (row >> 3)] =
                (__bf16)v;
          }
        }
      }
      __syncthreads();
      const int s0g = m0 >> 3;            // 32 s values per block
      const int hh = (n0 >> 6) & 15;      // base h (even) for this block
#pragma unroll
      for (int rr = 0; rr < 2; ++rr) {
        const int r = tid + rr * 512;     // 0..1023 rows: [hl][b][d]
        const int hl = r >> 9, bb = (r >> 6) & 7, dd = r & 63;
        __bf16* dst = outV + ((size_t)((bb * 16 + hh + hl) * 64 + dd) << 10) + s0g;
        const __bf16* src = &vtl[(size_t)r << 5];
#pragma unroll
        for (int j = 0; j < 4; ++j)
          *(bf16x8*)&dst[j * 8] = *(const bf16x8*)&src[j * 8];
      }
      return;
    }
  }

  // epilogue: per-wave 64x64 C block (4mf x 4nf frags)
#pragma unroll
  for (int mf = 0; mf < 4; ++mf) {
    const int gm0 = m0 + wr * 64 + mf * 16 + lg * 4;
#pragma unroll
    for (int nf = 0; nf < 4; ++nf) {
      const int gn = n0 + wc * 64 + nf * 16 + lr;
      const float bv = bias[gn];
#pragma unroll
      for (int rg = 0; rg < 4; ++rg) {
        const int gm = gm0 + rg;
        float v = acc[mf][nf][rg] + bv;
        if constexpr (EPI == 0) {
          int t = gn >> 10, h = (gn >> 6) & 15, d = gn & 63;
          int s = gm >> 3, b = gm & 7;
          if (t == 0) v *= 0.18033688011112042f;  // d^-0.5 * log2(e)
          outT[(((size_t)((t * 8 + b) * 16 + h) * 1024 + s) << 6) + d] = (__bf16)v;
        } else {
          outF[(size_t)gm * N + gn] = v;
        }
      }
    }
  }
}

// ---- attn per-tile macro: KT/KC/KS/VC/VS are LITERALS.
// Issue order: V(t+1) FIRST, then K(t+2) -> end-of-tile vmcnt(1) completes
// V(t+1)+K(t+1), leaves K(t+2) in flight (2-tile K budget, 1-tile V budget).
#define ATTN_TILE(KT, KC, KS, VC, VS)                                           \
  {                                                                             \
    if ((KT) < 15)                                                              \
      gload_lds16(vtp + (size_t)srow * 1024 + ((KT) + 1) * 64 + sc8,            \
                  &sV[VS][wave * 512]);                                         \
    if ((KT) < 14)                                                              \
      gload_lds16(kp + (size_t)((KT) * 64 + 128 + srow) * 64 + sc8,             \
                  &sK[KS][wave * 512]);                                         \
    f32x4 sf[4];                                                                \
    __builtin_amdgcn_s_setprio(1);                                              \
    _Pragma("unroll") for (int tj = 0; tj < 4; ++tj) {                          \
      const int t = tj * 16 + lr;                                               \
      bf16x8 bk0 = *(const bf16x8*)&sK[KC][t * 64 + ((lg ^ (t & 7)) * 8)];      \
      bf16x8 bk1 = *(const bf16x8*)&sK[KC][t * 64 + (((4 + lg) ^ (t & 7)) * 8)];\
      f32x4 z = {};                                                             \
      z = __builtin_amdgcn_mfma_f32_16x16x32_bf16(bk0, aq[0], z, 0, 0, 0);      \
      z = __builtin_amdgcn_mfma_f32_16x16x32_bf16(bk1, aq[1], z, 0, 0, 0);      \
      sf[tj] = z;                                                               \
    }                                                                           \
    __builtin_amdgcn_s_setprio(0);                                              \
    const bool inband = ((KT) * 64 <= sb + 24) && ((KT) * 64 + 63 >= sb - 9);   \
    if (inband) {                                                               \
      const float* bDrow = &sBD[wave][lr][0];                                   \
      _Pragma("unroll") for (int tj = 0; tj < 4; ++tj) {                        \
        _Pragma("unroll") for (int rg = 0; rg < 4; ++rg) {                      \
          const int t = (KT) * 64 + tj * 16 + lg * 4 + rg;                      \
          const int dd = t - s;                                                 \
          const int ad = dd < 0 ? -dd : dd;                                     \
          if (ad <= 9) {                                                        \
            const float val = sf[tj][rg] + bDrow[ad];                           \
            sf[tj][rg] = val;                                                   \
            band[wave][lr][dd + 9] = (__bf16)val;                               \
          }                                                                     \
        }                                                                       \
      }                                                                         \
    }                                                                           \
    float vm[4];                                                                \
    _Pragma("unroll") for (int tj = 0; tj < 4; ++tj)                            \
      vm[tj] = fmaxf(fmaxf(sf[tj][0], sf[tj][1]), fmaxf(sf[tj][2], sf[tj][3])); \
    float vmax = fmaxf(fmaxf(vm[0], vm[1]), fmaxf(vm[2], vm[3]));               \
    vmax = fmaxf(vmax, __shfl_xor(vmax, 16, 64));                               \
    vmax = fmaxf(vmax, __shfl_xor(vmax, 32, 64));                               \
    if (__any(vmax > m + 8.f)) {                                                \
      const float mn = fmaxf(m, vmax);                                          \
      const float scl = EXP2F(m - mn);                                          \
      m = mn;                                                                   \
      l *= scl;                                                                 \
      _Pragma("unroll") for (int dj = 0; dj < 4; ++dj)                          \
        _Pragma("unroll") for (int rg = 0; rg < 4; ++rg)                        \
          o_acc[dj][rg] *= scl;                                                 \
    }                                                                           \
    float rs[4];                                                                \
    _Pragma("unroll") for (int tj = 0; tj < 4; ++tj) {                          \
      float p0 = EXP2F(sf[tj][0] - m), p1 = EXP2F(sf[tj][1] - m);               \
      float p2 = EXP2F(sf[tj][2] - m), p3 = EXP2F(sf[tj][3] - m);               \
      sf[tj][0] = p0; sf[tj][1] = p1; sf[tj][2] = p2; sf[tj][3] = p3;           \
      rs[tj] = (p0 + p1) + (p2 + p3);                                           \
    }                                                                           \
    float rsum = (rs[0] + rs[1]) + (rs[2] + rs[3]);                             \
    rsum += __shfl_xor(rsum, 16, 64);                                           \
    rsum += __shfl_xor(rsum, 32, 64);                                           \
    l += rsum;                                                                  \
    bf16x4 pbv[4];                                                              \
    _Pragma("unroll") for (int tj = 0; tj < 4; ++tj) {                          \
      pbv[tj][0] = (__bf16)sf[tj][0]; pbv[tj][1] = (__bf16)sf[tj][1];           \
      pbv[tj][2] = (__bf16)sf[tj][2]; pbv[tj][3] = (__bf16)sf[tj][3];           \
    }                                                                           \
    __builtin_amdgcn_s_setprio(1);                                              \
    _Pragma("unroll") for (int tj = 0; tj < 4; ++tj) {                          \
      _Pragma("unroll") for (int dj = 0; dj < 4; ++dj) {                        \
        const int d = dj * 16 + lr;                                             \
        const int ch = (2 * tj + (lg >> 1)) ^ (d & 7);                          \
        const bf16x4 av = *(const bf16x4*)&sV[VC][d * 64 + ch * 8 + (lg & 1) * 4]; \
        PV_MFMA(o_acc[dj], av, pbv[tj]);                                        \
      }                                                                         \
    }                                                                           \
    __builtin_amdgcn_s_setprio(0);                                              \
    if ((KT) < 14) {                                                            \
      asm volatile("s_waitcnt vmcnt(1)" ::: "memory");                          \
    } else if ((KT) == 14) {                                                    \
      asm volatile("s_waitcnt vmcnt(0)" ::: "memory");                          \
    }                                                                           \
    if ((KT) < 15) __builtin_amdgcn_s_barrier();                                \
  }

// Flash attention w/ distance band, qk-bias FUSED.  8 waves, 16 q-rows/wave,
// KV tiles of 64.  Swapped QK^T, per-lane softmax, zero-shuffle PV via 16x16x16.
// K triple-buffered (2-ahead), V double-buffered (1-ahead), counted vmcnt.
// NO global loads inside the K-loop (bias from sBD LDS) -> vmcnt counts staging only.
__global__ __launch_bounds__(512) void attn_kernel(
    const __bf16* __restrict__ qkv, const __bf16* __restrict__ vt,
    const float* __restrict__ kde, const float* __restrict__ vde,
    __bf16* __restrict__ O) {
  __shared__ __align__(16) __bf16 sK[3][4096];   // [64 t][64 k], 16B-chunk XOR swizzled
  __shared__ __align__(16) __bf16 sV[2][4096];   // [64 d][64 t], 16B-chunk XOR swizzled
  __shared__ __bf16 band[8][16][20];             // band logits (log2 dom), slot=(t-s)+9
  __shared__ float sBD[8][16][10];               // fused qk distance bias per q-row
  const int tid = threadIdx.x, wave = tid >> 6, lane = tid & 63;
  const int lg = lane >> 4, lr = lane & 15;
  const int lid = (blockIdx.x & 7) * 128 + (blockIdx.x >> 3);
  const int bh = lid >> 3;
  const int stile = lid & 7;
  const int sb = stile * 128 + wave * 16;
  const int b = bh >> 4, h = bh & 15;
  const __bf16* qp = qkv + (size_t)bh * 65536;
  const __bf16* kp = qkv + (size_t)(128 + bh) * 65536;
  const __bf16* vtp = vt + (size_t)bh * 65536;

  const int srow = tid >> 3;
  const int sc8 = ((tid & 7) ^ (srow & 7)) * 8;

  // prologue staging: K0, V0, K1 (in this order; vmcnt(1) leaves K1 in flight)
  gload_lds16(kp + (size_t)srow * 64 + sc8, &sK[0][wave * 512]);
  gload_lds16(vtp + (size_t)srow * 1024 + sc8, &sV[0][wave * 512]);
  gload_lds16(kp + (size_t)(64 + srow) * 64 + sc8, &sK[1][wave * 512]);

  {
    __bf16* bf = &band[0][0][0];
    for (int i = tid; i < 8 * 16 * 20; i += 512) bf[i] = (__bf16)(-1e30f);
  }

  bf16x8 aq[2];
#pragma unroll
  for (int kk = 0; kk < 2; ++kk)
    aq[kk] = *(const bf16x8*)&qp[(size_t)(sb + lr) * 64 + kk * 32 + lg * 8];

  // ---- fused qk distance-bias: sBD[wave][lr][c] = q[s]·(kde[c]-kde[10]) ----
  {
    float kd10[16];
#pragma unroll
    for (int e = 0; e < 16; ++e)
      kd10[e] = kde[640 + (e >> 3) * 32 + lg * 8 + (e & 7)];
#pragma unroll
    for (int c = 0; c < 10; ++c) {
      float acc = 0.f;
#pragma unroll
      for (int e = 0; e < 16; ++e)
        acc += (float)aq[e >> 3][e & 7] *
               (kde[c * 64 + (e >> 3) * 32 + lg * 8 + (e & 7)] - kd10[e]);
      acc += __shfl_xor(acc, 16, 64);
      acc += __shfl_xor(acc, 32, 64);
      if (lg == 0) sBD[wave][lr][c] = acc;
    }
  }
  // kde loads drain the vmem queue past K0/V0/K1; the manual vmcnt(1) below is
  // then trivially satisfied.  No global loads inside the main loop.

  f32x4 o_acc[4] = {};
  float m = -1e30f, l = 0.f;
  const int s = sb + lr;  // this lane's q row (replicated across lg groups)

  asm volatile("s_waitcnt vmcnt(1)" ::: "memory");
  __builtin_amdgcn_s_barrier();

  //            KT  KC KS VC VS
  ATTN_TILE( 0, 0, 2, 0, 1)
  ATTN_TILE( 1, 1, 0, 1, 0)
  ATTN_TILE( 2, 2, 1, 0, 1)
  ATTN_TILE( 3, 0, 2, 1, 0)
  ATTN_TILE( 4, 1, 0, 0, 1)
  ATTN_TILE( 5, 2, 1, 1, 0)
  ATTN_TILE( 6, 0, 2, 0, 1)
  ATTN_TILE( 7, 1, 0, 1, 0)
  ATTN_TILE( 8, 2, 1, 0, 1)
  ATTN_TILE( 9, 0, 2, 1, 0)
  ATTN_TILE(10, 1, 0, 0, 1)
  ATTN_TILE(11, 2, 1, 1, 0)
  ATTN_TILE(12, 0, 2, 0, 1)
  ATTN_TILE(13, 1, 0, 1, 0)
  ATTN_TILE(14, 2, 1, 0, 1)
  ATTN_TILE(15, 0, 2, 1, 0)

  // ---- epilogue: normalize + v_dist band correction, write (s,b,h*d) bf16 ----
  const float inv = 1.f / l;
  float psum[10];
  psum[0] = EXP2F((float)band[wave][lr][9] - m);
#pragma unroll
  for (int c = 1; c < 10; ++c)
    psum[c] = EXP2F((float)band[wave][lr][9 - c] - m) +
              EXP2F((float)band[wave][lr][9 + c] - m);
#pragma unroll
  for (int dj = 0; dj < 4; ++dj) {
    bf16x4 ov;
#pragma unroll
    for (int rg = 0; rg < 4; ++rg) {
      const int d = dj * 16 + lg * 4 + rg;
      float acc2 = 0.f;
#pragma unroll
      for (int c = 0; c < 10; ++c)
        acc2 += psum[c] * (vde[c * 64 + d] - vde[640 + d]);
      ov[rg] = (__bf16)((o_acc[dj][rg] + acc2) * inv + vde[640 + d]);
    }
    *(bf16x4*)&O[((size_t)(s * 8 + b)) * 1024 + h * 64 + dj * 16 + lg * 4] = ov;
  }
}

extern "C" void kernel_launch(void* const* d_in, const int* in_sizes, int n_in,
                              void* d_out, int out_size, void* d_ws, size_t ws_size,
                              hipStream_t stream) {
  (void)in_sizes; (void)n_in; (void)out_size; (void)ws_size;
  const float* inputs = (const float*)d_in[0];
  const float* W_in   = (const float*)d_in[1];
  const float* b_in   = (const float*)d_in[2];
  const float* kde    = (const float*)d_in[3];
  const float* vde    = (const float*)d_in[4];
  const float* W_out  = (const float*)d_in[5];
  const float* b_out  = (const float*)d_in[6];
  float* out = (float*)d_out;

  char* ws = (char*)d_ws;
  __bf16* qkvt  = (__bf16*)(ws);              // (3,8,16,1024,64) bf16 (V third unused)
  __bf16* vt    = (__bf16*)(ws + 50331648);   // (128,64,1024)  bf16
  __bf16* Xb    = (__bf16*)(ws + 75497472);   // (8192,1024)    bf16
  __bf16* Ob    = (__bf16*)(ws + 75497472);   // reuse Xb region after GEMM1
  __bf16* Wb_in = (__bf16*)(ws + 92274688);   // (3072,1024)    bf16
  __bf16* Wb_out= (__bf16*)(ws + 98566144);   // (1024,1024)    bf16

  f2b3_kernel<<<6144, 256, 0, stream>>>(inputs, Xb, W_in, Wb_in, W_out, Wb_out);

  // GEMM1: 32 M-bands x 24 N-tiles = 768 blocks (3 FULL rounds, CPX=96)
  gemm8p<0><<<768, 512, 0, stream>>>(Xb, Wb_in, b_in, 1024, nullptr, qkvt, vt, 3072, 24, 96);
  attn_kernel<<<1024, 512, 0, stream>>>(qkvt, vt, kde, vde, Ob);
  // GEMM2: 32 x 8 = 256 blocks (1 FULL round, CPX=32)
  gemm8p<1><<<256, 512, 0, stream>>>(Ob, Wb_out, b_out, 1024, out, nullptr, nullptr, 1024, 8, 32);
}